// Round 4
// baseline (373.504 us; speedup 1.0000x reference)
//
#include <hip/hip_runtime.h>
#include <hip/hip_bf16.h>

#define N_ATOMS 131072
#define DQ 256
#define H1 512
#define NTYPES 4
#define TILE_M 64
#define NPAD (N_ATOMS + NTYPES * TILE_M)       // 131328 rows, 2052 tiles
#define BLOCK_SLOTS 64                         // gemm blocks per type

typedef __bf16 bf16x8 __attribute__((ext_vector_type(8)));
typedef float f32x16 __attribute__((ext_vector_type(16)));

// RNE pack of two fp32 into one u32 of two bf16 (low = a).
__device__ __forceinline__ unsigned int pack2(float a, float b) {
  unsigned int ua = __builtin_bit_cast(unsigned int, a);
  unsigned int ub = __builtin_bit_cast(unsigned int, b);
  ua += 0x7fffu + ((ua >> 16) & 1u);
  ub += 0x7fffu + ((ub >> 16) & 1u);
  return __builtin_amdgcn_perm(ub, ua, 0x07060302);
}
__device__ __forceinline__ unsigned short f2bf(float f) {
  unsigned int u = __builtin_bit_cast(unsigned int, f);
  u += 0x7fffu + ((u >> 16) & 1u);
  return (unsigned short)(u >> 16);
}
__device__ __forceinline__ float fast_tanh(float x) {
  float e = __expf(2.0f * x);
  return 1.0f - 2.0f * __builtin_amdgcn_rcpf(e + 1.0f);
}
template <int CTRL>
__device__ __forceinline__ float dpp_add(float s) {
  int v = __builtin_amdgcn_mov_dpp(__builtin_bit_cast(int, s), CTRL, 0xF, 0xF, true);
  return s + __builtin_bit_cast(float, v);
}

// ---------------------------------------------------------------------------
// prep: perm init + per-block Z histogram; blocks < 128 also transpose W0
// fp32 [t][k][n] -> bf16 chunks [t][kg2][n][8k] (coalesced via LDS tile).
// ---------------------------------------------------------------------------
__global__ __launch_bounds__(256) void prep_kernel(
    const float* __restrict__ W0, const int* __restrict__ Z,
    unsigned short* __restrict__ W0s, int* __restrict__ perm,
    int* __restrict__ blockcounts)
{
  __shared__ int lc[NTYPES];
  __shared__ __align__(16) unsigned short S[64][72];
  const int b = blockIdx.x, tid = threadIdx.x;
  const int gid = b * 256 + tid;

  for (int i = gid; i < NPAD; i += 512 * 256) perm[i] = -1;
  if (tid < NTYPES) lc[tid] = 0;
  __syncthreads();
  atomicAdd(&lc[Z[gid]], 1);     // grid 512*256 == N exactly

  if (b < 128) {
    const int nb = b & 7, kb = (b >> 3) & 3, t = b >> 5;
    const int kl = tid >> 4, nl = (tid & 15) * 4;
#pragma unroll
    for (int r = 0; r < 4; ++r) {
      const int k = r * 16 + kl;
      const float4 v = *(const float4*)&W0[((size_t)(t * DQ + kb * 64 + k)) * H1 + nb * 64 + nl];
      S[nl + 0][k] = f2bf(v.x);
      S[nl + 1][k] = f2bf(v.y);
      S[nl + 2][k] = f2bf(v.z);
      S[nl + 3][k] = f2bf(v.w);
    }
    __syncthreads();
#pragma unroll
    for (int r = 0; r < 2; ++r) {
      const int c = r * 256 + tid;
      const int n = c & 63, kg2l = c >> 6;
      const uint4 v = *(const uint4*)&S[n][kg2l * 8];
      ((uint4*)W0s)[(size_t)(t * 32 + kb * 8 + kg2l) * H1 + nb * 64 + n] = v;
    }
  }
  __syncthreads();
  if (tid < NTYPES) blockcounts[b * NTYPES + tid] = lc[tid];
}

__global__ __launch_bounds__(256) void scan_kernel(
    const int* __restrict__ blockcounts, int* __restrict__ padded_off,
    int* __restrict__ cursors)
{
  __shared__ int sums[NTYPES];
  const int tid = threadIdx.x;
  if (tid < NTYPES) sums[tid] = 0;
  __syncthreads();
  const int t = tid & 3;
  int acc = 0;
  for (int b = tid >> 2; b < 512; b += 64) acc += blockcounts[b * 4 + t];
  atomicAdd(&sums[t], acc);
  __syncthreads();
  if (tid == 0) {
    int off = 0;
#pragma unroll
    for (int i = 0; i < NTYPES; ++i) {
      padded_off[i] = off;
      cursors[i] = off;
      off += (sums[i] + TILE_M - 1) & ~(TILE_M - 1);
    }
    padded_off[NTYPES] = off;
  }
}

__global__ __launch_bounds__(256) void scatter_kernel(
    const int* __restrict__ Z, int* __restrict__ cursors, int* __restrict__ perm)
{
  __shared__ int lc[NTYPES], lbase[NTYPES];
  const int tid = threadIdx.x;
  const int gid = blockIdx.x * 256 + tid;
  if (tid < NTYPES) lc[tid] = 0;
  __syncthreads();
  const int t  = Z[gid];
  const int my = atomicAdd(&lc[t], 1);
  __syncthreads();
  if (tid < NTYPES) lbase[tid] = lc[tid] ? atomicAdd(&cursors[tid], lc[tid]) : 0;
  __syncthreads();
  perm[lbase[t] + my] = gid;
}

// ---------------------------------------------------------------------------
// gather: one wave per q row. Coalesced 1 KB row load, bf16 pack, store into
// qs in per-tile MFMA-fragment layout [tile][kg2][row][8]. Pure streaming,
// no LDS, no barriers -> HBM-bound with huge TLP.
// ---------------------------------------------------------------------------
__device__ __forceinline__ void gather_row(const float* __restrict__ q,
    const int* __restrict__ perm, unsigned short* __restrict__ qs,
    int r, int l)
{
  const int atom = perm[r];
  uint2 u;
  if (atom >= 0) {
    const float4 v = *(const float4*)(q + (size_t)atom * DQ + l * 4);
    u.x = pack2(v.x, v.y);
    u.y = pack2(v.z, v.w);
  } else {
    u.x = 0u; u.y = 0u;       // padded row -> zeros (MFMA-safe)
  }
  unsigned short* tb = qs + (size_t)(r >> 6) * (32 * 64 * 8);
  *(uint2*)&tb[(((l >> 1) * 64) + (r & 63)) * 8 + (l & 1) * 4] = u;
}

__global__ __launch_bounds__(256) void gather_kernel(
    const float* __restrict__ q, const int* __restrict__ perm,
    const int* __restrict__ padded_off, unsigned short* __restrict__ qs)
{
  const int wid = (blockIdx.x * 256 + threadIdx.x) >> 6;   // 0..4103
  const int l = threadIdx.x & 63;
  const int total = padded_off[NTYPES];
  const int r0 = wid * 32;
  if (r0 + 32 <= total) {
#pragma unroll 4
    for (int i = 0; i < 32; ++i) gather_row(q, perm, qs, r0 + i, l);
  } else {
    for (int i = 0; i < 32; ++i) {
      const int r = r0 + i;
      if (r < total) gather_row(q, perm, qs, r, l);
    }
  }
}

// ---------------------------------------------------------------------------
// gemm: 256 blocks (1/CU), 8 waves, each wave owns 64 cols with B in VGPRs
// (loaded once). A read straight from pre-gathered qs (coalesced, L1/L2-hot,
// addresses data-independent). NO LDS staging, no K-loop barriers; ONE
// barrier per tile (epilogue), Fws parity-double-buffered.
// ---------------------------------------------------------------------------
__global__ __launch_bounds__(512, 2) void gemm_kernel(
    const unsigned short* __restrict__ qs, const int* __restrict__ perm,
    const int* __restrict__ padded_off, const unsigned short* __restrict__ W0s,
    const float* __restrict__ b0, const float* __restrict__ W1,
    const float* __restrict__ b1p, float* __restrict__ out)
{
  __shared__ float Fws[2][8][64];

  const int tid = threadIdx.x;
  const int w = tid >> 6, l = tid & 63;
  const int half = l >> 5, ln = l & 31;

  const int t = blockIdx.x >> 6;
  const int bslot = blockIdx.x & (BLOCK_SLOTS - 1);
  const int seg0 = padded_off[t];
  const int ntiles = (padded_off[t + 1] - seg0) >> 6;
  if (bslot >= ntiles) return;

  const int colbase = w * 64;

  float b0v[2], w1v[2];
#pragma unroll
  for (int nt = 0; nt < 2; ++nt) {
    const int c = colbase + nt * 32 + ln;
    b0v[nt] = b0[t * H1 + c];
    w1v[nt] = W1[t * H1 + c];
  }
  const float b1 = b1p[0];

  // ---- B slice -> registers, once per block ----
  const unsigned short* Bt = W0s + (size_t)t * (DQ * H1);
  bf16x8 Bf[16][2];
#pragma unroll
  for (int ks = 0; ks < 16; ++ks) {
    const int kg2 = ks * 2 + half;
#pragma unroll
    for (int nt = 0; nt < 2; ++nt)
      Bf[ks][nt] = *(const bf16x8*)(Bt + ((size_t)kg2 * H1 + colbase + nt * 32 + ln) * 8);
  }

  int parity = 0;
  for (int j = bslot; j < ntiles; j += BLOCK_SLOTS, parity ^= 1) {
    const int row0 = seg0 + (j << 6);
    const unsigned short* At = qs + (size_t)row0 * 256;   // tile base (MFMA layout)

    f32x16 acc[2][2];
#pragma unroll
    for (int mt = 0; mt < 2; ++mt)
#pragma unroll
      for (int nt = 0; nt < 2; ++nt) acc[mt][nt] = (f32x16)0.0f;

    // barrier-free K-loop: coalesced global A loads + MFMA, compiler-pipelined
#pragma unroll
    for (int g = 0; g < 4; ++g) {
      bf16x8 Ab[4][2];
#pragma unroll
      for (int ks = 0; ks < 4; ++ks) {
        const int kg2 = (g * 4 + ks) * 2 + half;
        Ab[ks][0] = *(const bf16x8*)&At[(kg2 * 64 + ln) * 8];
        Ab[ks][1] = *(const bf16x8*)&At[(kg2 * 64 + 32 + ln) * 8];
      }
#pragma unroll
      for (int ks = 0; ks < 4; ++ks) {
        const int k = g * 4 + ks;
        acc[0][0] = __builtin_amdgcn_mfma_f32_32x32x16_bf16(Ab[ks][0], Bf[k][0], acc[0][0], 0, 0, 0);
        acc[1][0] = __builtin_amdgcn_mfma_f32_32x32x16_bf16(Ab[ks][1], Bf[k][0], acc[1][0], 0, 0, 0);
        acc[0][1] = __builtin_amdgcn_mfma_f32_32x32x16_bf16(Ab[ks][0], Bf[k][1], acc[0][1], 0, 0, 0);
        acc[1][1] = __builtin_amdgcn_mfma_f32_32x32x16_bf16(Ab[ks][1], Bf[k][1], acc[1][1], 0, 0, 0);
      }
    }

    // ---- epilogue: tanh + W1-dot; butterfly (3 DPP + 2 swizzle stages) ----
#pragma unroll
    for (int mt = 0; mt < 2; ++mt) {
#pragma unroll
      for (int r = 0; r < 16; ++r) {
        float s = w1v[0] * fast_tanh(acc[mt][0][r] + b0v[0])
                + w1v[1] * fast_tanh(acc[mt][1][r] + b0v[1]);
        s = dpp_add<0xB1>(s);           // xor 1
        s = dpp_add<0x4E>(s);           // xor 2
        s += __shfl_xor(s, 4);          // xor 4
        s = dpp_add<0x128>(s);          // xor 8 (row_ror:8)
        s += __shfl_xor(s, 16);         // xor 16
        if (ln == 0)
          Fws[parity][w][mt * 32 + (r & 3) + 8 * (r >> 2) + 4 * half] = s;
      }
    }
    __syncthreads();   // the ONLY barrier per tile

    if (tid < TILE_M) {
      const int atom = perm[row0 + tid];
      if (atom >= 0) {
        float f = b1;
#pragma unroll
        for (int ww = 0; ww < 8; ++ww) f += Fws[parity][ww][tid];
        out[atom] = f;
      }
    }
    // no second barrier: next tile writes Fws[parity^1]
  }
}

extern "C" void kernel_launch(void* const* d_in, const int* in_sizes, int n_in,
                              void* d_out, int out_size, void* d_ws, size_t ws_size,
                              hipStream_t stream) {
  const float* q  = (const float*)d_in[0];
  const int*   Z  = (const int*)d_in[1];
  const float* W0 = (const float*)d_in[2];
  const float* b0 = (const float*)d_in[3];
  const float* W1 = (const float*)d_in[4];
  const float* b1 = (const float*)d_in[5];
  float* out = (float*)d_out;

  char* ws = (char*)d_ws;
  int* blockcounts = (int*)(ws);                                   // 8 KB
  int* padded_off  = (int*)(ws + 8192);                            // 5 ints
  int* cursors     = (int*)(ws + 8192 + 32);                       // 4 ints
  int* perm        = (int*)(ws + 8192 + 64);                       // NPAD ints = 513 KB
  unsigned short* W0s = (unsigned short*)(ws + 8192 + 64 + (size_t)NPAD * 4);  // 1 MB
  unsigned short* qs  = (unsigned short*)(ws + 8192 + 64 + (size_t)NPAD * 4
                                          + (size_t)NTYPES * DQ * H1 * 2);     // 64.1 MB

  hipLaunchKernelGGL(prep_kernel,    dim3(512),  dim3(256), 0, stream, W0, Z, W0s, perm, blockcounts);
  hipLaunchKernelGGL(scan_kernel,    dim3(1),    dim3(256), 0, stream, blockcounts, padded_off, cursors);
  hipLaunchKernelGGL(scatter_kernel, dim3(512),  dim3(256), 0, stream, Z, cursors, perm);
  hipLaunchKernelGGL(gather_kernel,  dim3(1026), dim3(256), 0, stream, q, perm, padded_off, qs);
  hipLaunchKernelGGL(gemm_kernel,    dim3(NTYPES * BLOCK_SLOTS), dim3(512), 0, stream,
                     qs, perm, padded_off, W0s, b0, W1, b1, out);
}

// Round 5
// 318.246 us; speedup vs baseline: 1.1736x; 1.1736x over previous
//
#include <hip/hip_runtime.h>
#include <hip/hip_bf16.h>

#define N_ATOMS 131072
#define DQ 256
#define H1 512
#define NTYPES 4
#define TILE_M 64
#define NPAD (N_ATOMS + NTYPES * TILE_M)       // 131328 rows = 2052 tiles
#define NTILES (NPAD / TILE_M)                 // 2052
#define BLOCK_SLOTS 64                         // gemm blocks per type

typedef __bf16 bf16x8 __attribute__((ext_vector_type(8)));
typedef float f32x16 __attribute__((ext_vector_type(16)));

// RNE pack of two fp32 into one u32 of two bf16 (low = a).
__device__ __forceinline__ unsigned int pack2(float a, float b) {
  unsigned int ua = __builtin_bit_cast(unsigned int, a);
  unsigned int ub = __builtin_bit_cast(unsigned int, b);
  ua += 0x7fffu + ((ua >> 16) & 1u);
  ub += 0x7fffu + ((ub >> 16) & 1u);
  return __builtin_amdgcn_perm(ub, ua, 0x07060302);
}
__device__ __forceinline__ unsigned short f2bf(float f) {
  unsigned int u = __builtin_bit_cast(unsigned int, f);
  u += 0x7fffu + ((u >> 16) & 1u);
  return (unsigned short)(u >> 16);
}
__device__ __forceinline__ float fast_tanh(float x) {
  float e = __expf(2.0f * x);
  return 1.0f - 2.0f * __builtin_amdgcn_rcpf(e + 1.0f);
}
template <int CTRL>
__device__ __forceinline__ float dpp_add(float s) {
  int v = __builtin_amdgcn_mov_dpp(__builtin_bit_cast(int, s), CTRL, 0xF, 0xF, true);
  return s + __builtin_bit_cast(float, v);
}

// ---------------------------------------------------------------------------
// prep: perm init + per-block Z histogram; blocks < 128 also transpose W0
// fp32 [t][k][n] -> bf16 chunks [t][kg2][n][8k] (coalesced via LDS tile).
// ---------------------------------------------------------------------------
__global__ __launch_bounds__(256) void prep_kernel(
    const float* __restrict__ W0, const int* __restrict__ Z,
    unsigned short* __restrict__ W0s, int* __restrict__ perm,
    int* __restrict__ blockcounts)
{
  __shared__ int lc[NTYPES];
  __shared__ __align__(16) unsigned short S[64][72];
  const int b = blockIdx.x, tid = threadIdx.x;
  const int gid = b * 256 + tid;

  for (int i = gid; i < NPAD; i += 512 * 256) perm[i] = -1;
  if (tid < NTYPES) lc[tid] = 0;
  __syncthreads();
  atomicAdd(&lc[Z[gid]], 1);     // grid 512*256 == N exactly

  if (b < 128) {
    const int nb = b & 7, kb = (b >> 3) & 3, t = b >> 5;
    const int kl = tid >> 4, nl = (tid & 15) * 4;
#pragma unroll
    for (int r = 0; r < 4; ++r) {
      const int k = r * 16 + kl;
      const float4 v = *(const float4*)&W0[((size_t)(t * DQ + kb * 64 + k)) * H1 + nb * 64 + nl];
      S[nl + 0][k] = f2bf(v.x);
      S[nl + 1][k] = f2bf(v.y);
      S[nl + 2][k] = f2bf(v.z);
      S[nl + 3][k] = f2bf(v.w);
    }
    __syncthreads();
#pragma unroll
    for (int r = 0; r < 2; ++r) {
      const int c = r * 256 + tid;
      const int n = c & 63, kg2l = c >> 6;
      const uint4 v = *(const uint4*)&S[n][kg2l * 8];
      ((uint4*)W0s)[(size_t)(t * 32 + kb * 8 + kg2l) * H1 + nb * 64 + n] = v;
    }
  }
  __syncthreads();
  if (tid < NTYPES) blockcounts[b * NTYPES + tid] = lc[tid];
}

__global__ __launch_bounds__(256) void scan_kernel(
    const int* __restrict__ blockcounts, int* __restrict__ padded_off,
    int* __restrict__ cursors)
{
  __shared__ int sums[NTYPES];
  const int tid = threadIdx.x;
  if (tid < NTYPES) sums[tid] = 0;
  __syncthreads();
  const int t = tid & 3;
  int acc = 0;
  for (int b = tid >> 2; b < 512; b += 64) acc += blockcounts[b * 4 + t];
  atomicAdd(&sums[t], acc);
  __syncthreads();
  if (tid == 0) {
    int off = 0;
#pragma unroll
    for (int i = 0; i < NTYPES; ++i) {
      padded_off[i] = off;
      cursors[i] = off;
      off += (sums[i] + TILE_M - 1) & ~(TILE_M - 1);
    }
    padded_off[NTYPES] = off;
  }
}

__global__ __launch_bounds__(256) void scatter_kernel(
    const int* __restrict__ Z, int* __restrict__ cursors, int* __restrict__ perm)
{
  __shared__ int lc[NTYPES], lbase[NTYPES];
  const int tid = threadIdx.x;
  const int gid = blockIdx.x * 256 + tid;
  if (tid < NTYPES) lc[tid] = 0;
  __syncthreads();
  const int t  = Z[gid];
  const int my = atomicAdd(&lc[t], 1);
  __syncthreads();
  if (tid < NTYPES) lbase[tid] = lc[tid] ? atomicAdd(&cursors[tid], lc[tid]) : 0;
  __syncthreads();
  perm[lbase[t] + my] = gid;
}

// ---------------------------------------------------------------------------
// gather: one block per 64-row tile. Coalesced row reads (1 wave-instr =
// 1 KB of one q row) -> bf16 pack -> row-major LDS (+pad) -> barrier ->
// fragment-order ds_read_b128 -> PERFECTLY SEQUENTIAL 32 KB qs tile store.
// Fixes R4's 3.4x write amplification (16B scatter stores).
// ---------------------------------------------------------------------------
#define ROWSTR 264   // 256 + 8 shorts pad (528 B rows: breaks bank alignment)

__global__ __launch_bounds__(256) void gather_kernel(
    const float* __restrict__ q, const int* __restrict__ perm,
    const int* __restrict__ padded_off, unsigned short* __restrict__ qs)
{
  __shared__ __align__(16) unsigned short S[64 * ROWSTR];   // 33 KB

  const int tile = blockIdx.x;
  const int total_tiles = padded_off[NTYPES] >> 6;
  if (tile >= total_tiles) return;

  const int tid = threadIdx.x;
  const int w = tid >> 6, l = tid & 63;
  const int row0 = tile * TILE_M;

  int atoms[16];
#pragma unroll
  for (int i = 0; i < 16; ++i) atoms[i] = perm[row0 + w * 16 + i];

#pragma unroll
  for (int i = 0; i < 16; ++i) {
    const int row = w * 16 + i;
    uint2 u;
    if (atoms[i] >= 0) {
      const float4 v = *(const float4*)(q + (size_t)atoms[i] * DQ + l * 4);
      u.x = pack2(v.x, v.y);
      u.y = pack2(v.z, v.w);
    } else {
      u.x = 0u; u.y = 0u;
    }
    *(uint2*)&S[row * ROWSTR + l * 4] = u;
  }
  __syncthreads();

  unsigned short* qt = qs + (size_t)tile * (32 * 64 * 8);
#pragma unroll
  for (int p = 0; p < 8; ++p) {
    const int c = p * 256 + tid;          // chunk id = kg2*64 + row
    const int row = c & 63, kg2 = c >> 6;
    const uint4 v = *(const uint4*)&S[row * ROWSTR + kg2 * 8];
    *(uint4*)&qt[(size_t)c * 8] = v;      // wave writes 1 KB contiguous
  }
}

// ---------------------------------------------------------------------------
// gemm: 256 blocks (1/CU), 8 waves, each wave owns 64 cols with B in VGPRs
// (loaded once). A read straight from pre-gathered qs (coalesced, addresses
// data-independent). No LDS staging, no K-loop barriers; ONE barrier per
// tile (epilogue), Fws parity-double-buffered.
// ---------------------------------------------------------------------------
__global__ __launch_bounds__(512, 2) void gemm_kernel(
    const unsigned short* __restrict__ qs, const int* __restrict__ perm,
    const int* __restrict__ padded_off, const unsigned short* __restrict__ W0s,
    const float* __restrict__ b0, const float* __restrict__ W1,
    const float* __restrict__ b1p, float* __restrict__ out)
{
  __shared__ float Fws[2][8][64];

  const int tid = threadIdx.x;
  const int w = tid >> 6, l = tid & 63;
  const int half = l >> 5, ln = l & 31;

  const int t = blockIdx.x >> 6;
  const int bslot = blockIdx.x & (BLOCK_SLOTS - 1);
  const int seg0 = padded_off[t];
  const int ntiles = (padded_off[t + 1] - seg0) >> 6;
  if (bslot >= ntiles) return;

  const int colbase = w * 64;

  float b0v[2], w1v[2];
#pragma unroll
  for (int nt = 0; nt < 2; ++nt) {
    const int c = colbase + nt * 32 + ln;
    b0v[nt] = b0[t * H1 + c];
    w1v[nt] = W1[t * H1 + c];
  }
  const float b1 = b1p[0];

  // ---- B slice -> registers, once per block ----
  const unsigned short* Bt = W0s + (size_t)t * (DQ * H1);
  bf16x8 Bf[16][2];
#pragma unroll
  for (int ks = 0; ks < 16; ++ks) {
    const int kg2 = ks * 2 + half;
#pragma unroll
    for (int nt = 0; nt < 2; ++nt)
      Bf[ks][nt] = *(const bf16x8*)(Bt + ((size_t)kg2 * H1 + colbase + nt * 32 + ln) * 8);
  }

  int parity = 0;
  for (int j = bslot; j < ntiles; j += BLOCK_SLOTS, parity ^= 1) {
    const int row0 = seg0 + (j << 6);
    const unsigned short* At = qs + (size_t)row0 * 256;   // tile base (frag layout)

    f32x16 acc[2][2];
#pragma unroll
    for (int mt = 0; mt < 2; ++mt)
#pragma unroll
      for (int nt = 0; nt < 2; ++nt) acc[mt][nt] = (f32x16)0.0f;

#pragma unroll
    for (int g = 0; g < 4; ++g) {
      bf16x8 Ab[4][2];
#pragma unroll
      for (int ks = 0; ks < 4; ++ks) {
        const int kg2 = (g * 4 + ks) * 2 + half;
        Ab[ks][0] = *(const bf16x8*)&At[(kg2 * 64 + ln) * 8];
        Ab[ks][1] = *(const bf16x8*)&At[(kg2 * 64 + 32 + ln) * 8];
      }
#pragma unroll
      for (int ks = 0; ks < 4; ++ks) {
        const int k = g * 4 + ks;
        acc[0][0] = __builtin_amdgcn_mfma_f32_32x32x16_bf16(Ab[ks][0], Bf[k][0], acc[0][0], 0, 0, 0);
        acc[1][0] = __builtin_amdgcn_mfma_f32_32x32x16_bf16(Ab[ks][1], Bf[k][0], acc[1][0], 0, 0, 0);
        acc[0][1] = __builtin_amdgcn_mfma_f32_32x32x16_bf16(Ab[ks][0], Bf[k][1], acc[0][1], 0, 0, 0);
        acc[1][1] = __builtin_amdgcn_mfma_f32_32x32x16_bf16(Ab[ks][1], Bf[k][1], acc[1][1], 0, 0, 0);
      }
    }

    // ---- epilogue: tanh + W1-dot; butterfly (3 DPP + 2 swizzle stages) ----
#pragma unroll
    for (int mt = 0; mt < 2; ++mt) {
#pragma unroll
      for (int r = 0; r < 16; ++r) {
        float s = w1v[0] * fast_tanh(acc[mt][0][r] + b0v[0])
                + w1v[1] * fast_tanh(acc[mt][1][r] + b0v[1]);
        s = dpp_add<0xB1>(s);           // xor 1
        s = dpp_add<0x4E>(s);           // xor 2
        s += __shfl_xor(s, 4);          // xor 4
        s = dpp_add<0x128>(s);          // xor 8 (row_ror:8)
        s += __shfl_xor(s, 16);         // xor 16
        if (ln == 0)
          Fws[parity][w][mt * 32 + (r & 3) + 8 * (r >> 2) + 4 * half] = s;
      }
    }
    __syncthreads();   // the ONLY barrier per tile

    if (tid < TILE_M) {
      const int atom = perm[row0 + tid];
      if (atom >= 0) {
        float f = b1;
#pragma unroll
        for (int ww = 0; ww < 8; ++ww) f += Fws[parity][ww][tid];
        out[atom] = f;
      }
    }
    // no second barrier: next tile writes Fws[parity^1]
  }
}

extern "C" void kernel_launch(void* const* d_in, const int* in_sizes, int n_in,
                              void* d_out, int out_size, void* d_ws, size_t ws_size,
                              hipStream_t stream) {
  const float* q  = (const float*)d_in[0];
  const int*   Z  = (const int*)d_in[1];
  const float* W0 = (const float*)d_in[2];
  const float* b0 = (const float*)d_in[3];
  const float* W1 = (const float*)d_in[4];
  const float* b1 = (const float*)d_in[5];
  float* out = (float*)d_out;

  char* ws = (char*)d_ws;
  int* blockcounts = (int*)(ws);                                   // 8 KB
  int* padded_off  = (int*)(ws + 8192);                            // 5 ints
  int* cursors     = (int*)(ws + 8192 + 32);                       // 4 ints
  int* perm        = (int*)(ws + 8192 + 64);                       // NPAD ints
  unsigned short* W0s = (unsigned short*)(ws + 8192 + 64 + (size_t)NPAD * 4);  // 1 MB
  unsigned short* qs  = (unsigned short*)(ws + 8192 + 64 + (size_t)NPAD * 4
                                          + (size_t)NTYPES * DQ * H1 * 2);     // 64.2 MB

  hipLaunchKernelGGL(prep_kernel,    dim3(512),    dim3(256), 0, stream, W0, Z, W0s, perm, blockcounts);
  hipLaunchKernelGGL(scan_kernel,    dim3(1),      dim3(256), 0, stream, blockcounts, padded_off, cursors);
  hipLaunchKernelGGL(scatter_kernel, dim3(512),    dim3(256), 0, stream, Z, cursors, perm);
  hipLaunchKernelGGL(gather_kernel,  dim3(NTILES), dim3(256), 0, stream, q, perm, padded_off, qs);
  hipLaunchKernelGGL(gemm_kernel,    dim3(NTYPES * BLOCK_SLOTS), dim3(512), 0, stream,
                     qs, perm, padded_off, W0s, b0, W1, b1, out);
}